// Round 10
// baseline (570.272 us; speedup 1.0000x reference)
//
#include <hip/hip_runtime.h>
#include <hip/hip_bf16.h>

#define NN 100000
#define EE 1250000
#define PAD 48   // max degree slack: Poisson(12.5) P(deg>=48) ~ 2e-13/node

#define RL(x, l) __builtin_amdgcn_readlane((x), (l))
#define RLF(x, l) __int_as_float(__builtin_amdgcn_readlane(__float_as_int(x), (l)))

__device__ __forceinline__ unsigned short bf16rtn(float x) {
    unsigned u = __float_as_uint(x);
    unsigned r = u + 0x7fffu + ((u >> 16) & 1u);
    return (unsigned short)(r >> 16);
}
__device__ __forceinline__ float bflo(unsigned u) { return __uint_as_float(u << 16); }
__device__ __forceinline__ float bfhi(unsigned u) { return __uint_as_float(u & 0xffff0000u); }

// ---------------- CSR build (single pass, padded rows) ----------------
// One returning atomic per edge (~23 G atomics/s fabric ceiling, R2/R5/R9
// measured) + direct scatter into the padded row. Replaces the old
// count+bsum+scan+fill 4-dispatch chain; rowptr no longer exists.
__global__ __launch_bounds__(256) void k_cfill(const int* __restrict__ ei,
                                               const float* __restrict__ ew,
                                               int* __restrict__ cnt,
                                               int2* __restrict__ epad) {
    int e = blockIdx.x * 256 + threadIdx.x;
    if (e >= EE) return;
    int s = __builtin_nontemporal_load(&ei[e]);
    int d = __builtin_nontemporal_load(&ei[EE + e]);
    float w = __builtin_nontemporal_load(&ew[e]);
    int sl = atomicAdd(&cnt[d], 1);
    if (sl < PAD) epad[d * PAD + sl] = make_int2(s, __float_as_int(w));
}

// deg[n] = 1 + sum_row ew -> dinv[n], xd[n] = dinv[n]*x[n].  4 nodes/wave.
__global__ __launch_bounds__(256) void k_deg(const int* __restrict__ cnt,
                                             const int2* __restrict__ ep,
                                             const float* __restrict__ x,
                                             float* __restrict__ dinv,
                                             float* __restrict__ xd) {
    int lane = threadIdx.x & 63;
    int wid  = threadIdx.x >> 6;
    int l16  = lane & 15;
    int sub  = lane >> 4;
    int node = (blockIdx.x * 4 + wid) * 4 + sub;
    if (node >= NN) return;
    int beg = node * PAD;
    int end = beg + min(cnt[node], PAD);
    float s = 0.f;
    for (int idx = beg + l16; idx < end; idx += 16)
        s += __int_as_float(ep[idx].y);
    #pragma unroll
    for (int m = 8; m >= 1; m >>= 1) s += __shfl_xor(s, m, 64);
    if (l16 == 0) {
        float di = rsqrtf(s + 1.0f);
        dinv[node] = di;
        xd[node] = di * x[node];
    }
}

// ---------------- Layers ----------------
// Identity: Agg_l[d] = dinv_d * ( G'_l[d] + sum_e w_e * G'_l[src] ), G' = dinv (.) G.
// G' stored in bf16 (64 feats = 32 uints/row). Y and all accumulation fp32.

// Layer 1: z scalar agg + matvec, W2 via LDS (amortized over 4 nodes/wave). grid NN/16.
__global__ __launch_bounds__(256) void k_l1(
    const float* __restrict__ xd, const float* __restrict__ dinv,
    const int* __restrict__ cnt, const int2* __restrict__ ep,
    const float* __restrict__ W1, const float* __restrict__ b1,
    const float* __restrict__ W2, unsigned short* __restrict__ Gout)
{
    __shared__ float sW[4096];
    int tid = threadIdx.x;
    #pragma unroll
    for (int i = 0; i < 16; ++i) sW[tid + i * 256] = W2[tid + i * 256];
    __syncthreads();
    int lane = tid & 63, l16 = lane & 15, sub = lane >> 4;
    int g4 = blockIdx.x * 4 + (tid >> 6);
    int nodeS = g4 * 4 + sub;
    int beg = nodeS * PAD;
    int end = beg + min(cnt[nodeS], PAD);
    float partial = 0.f;
    for (int idx = beg + l16; idx < end; idx += 16) {
        int2 p = ep[idx];
        partial = fmaf(__int_as_float(p.y), xd[p.x], partial);
    }
    #pragma unroll
    for (int m = 8; m >= 1; m >>= 1) partial += __shfl_xor(partial, m, 64);
    float z = dinv[nodeS] * (xd[nodeS] + partial);   // valid where l16==0
    float z0 = RLF(z, 0), z1 = RLF(z, 16), z2 = RLF(z, 32), z3 = RLF(z, 48);
    float w1l = W1[lane], b1l = b1[lane];
    float v0 = fmaxf(fmaf(z0, w1l, b1l), 0.f);
    float v1 = fmaxf(fmaf(z1, w1l, b1l), 0.f);
    float v2 = fmaxf(fmaf(z2, w1l, b1l), 0.f);
    float v3 = fmaxf(fmaf(z3, w1l, b1l), 0.f);
    float a0 = 0.f, a1 = 0.f, a2 = 0.f, a3 = 0.f;
    #pragma unroll
    for (int k = 0; k < 64; ++k) {
        float wk = sW[k * 64 + lane];
        a0 = fmaf(RLF(v0, k), wk, a0);
        a1 = fmaf(RLF(v1, k), wk, a1);
        a2 = fmaf(RLF(v2, k), wk, a2);
        a3 = fmaf(RLF(v3, k), wk, a3);
    }
    int n0 = g4 * 4;
    Gout[(n0 + 0) * 64 + lane] = bf16rtn(dinv[n0 + 0] * a0);
    Gout[(n0 + 1) * 64 + lane] = bf16rtn(dinv[n0 + 1] * a1);
    Gout[(n0 + 2) * 64 + lane] = bf16rtn(dinv[n0 + 2] * a2);
    Gout[(n0 + 3) * 64 + lane] = bf16rtn(dinv[n0 + 3] * a3);
}

// Gather over bf16 rows: Y[d] = dinv_d * ( G'[d] + sum_e w_e * G'[src] ).
// R7-proven shape: one wave per node; 16-edge batches (8 row-loads in flight,
// 2 edges per load via wave halves); ep indices wave-uniform -> s_load;
// masked tail clamps to ep[j] (j < end => initialized). grid = NN/4.
__global__ __launch_bounds__(256) void k_gather(
    const unsigned* __restrict__ G16, const float* __restrict__ dinv,
    const int* __restrict__ cnt, const int2* __restrict__ ep,
    float* __restrict__ Y)
{
    int tid = threadIdx.x;
    int lane = tid & 63;
    int lc = lane & 31;
    int half = lane >> 5;
    int node = blockIdx.x * 4 + (tid >> 6);
    int m = __builtin_amdgcn_readfirstlane(cnt[node]);
    m = min(m, PAD);
    int beg = node * PAD;
    int end = beg + m;
    float ax = 0.f, ay = 0.f;
    if (half == 0) {
        unsigned u = G16[node * 32 + lc];
        ax = bflo(u); ay = bfhi(u);
    }
    int j = beg;
    for (; j + 16 <= end; j += 16) {          // full batch: 16 edges, 8 loads
        unsigned u[8]; float nv[8];
        #pragma unroll
        for (int t = 0; t < 8; ++t) {
            int2 pa = ep[j + t];              // uniform -> s_load
            int2 pb = ep[j + 8 + t];          // uniform -> s_load
            int src = half ? pb.x : pa.x;
            nv[t] = __int_as_float(half ? pb.y : pa.y);
            u[t] = G16[src * 32 + lc];
        }
        #pragma unroll
        for (int t = 0; t < 8; ++t) {
            ax = fmaf(bflo(u[t]), nv[t], ax);
            ay = fmaf(bfhi(u[t]), nv[t], ay);
        }
    }
    if (j < end) {                            // masked batch (tail 1..15)
        unsigned u[8]; float nv[8];
        #pragma unroll
        for (int t = 0; t < 8; ++t) {
            int ia = j + t, ib = j + 8 + t;   // uniform
            int2 pa = ep[ia < end ? ia : j];
            int2 pb = ep[ib < end ? ib : j];
            int src = half ? pb.x : pa.x;
            float w = __int_as_float(half ? pb.y : pa.y);
            bool v = half ? (ib < end) : (ia < end);
            nv[t] = v ? w : 0.f;
            u[t] = G16[src * 32 + lc];
        }
        #pragma unroll
        for (int t = 0; t < 8; ++t) {
            ax = fmaf(bflo(u[t]), nv[t], ax);
            ay = fmaf(bfhi(u[t]), nv[t], ay);
        }
    }
    ax += __shfl_xor(ax, 32, 64);
    ay += __shfl_xor(ay, 32, 64);
    if (half == 0) {
        float din = dinv[node];
        float2 o = make_float2(din * ax, din * ay);
        *((float2*)(Y + (size_t)node * 64) + lc) = o;
    }
}

// G' = dinv (.) ( relu(Y + bias) @ W ), bf16 out — 4 nodes/wave, W in VGPRs. grid NN/16.
__global__ __launch_bounds__(256, 4) void k_mv(
    const float* __restrict__ Y, const float* __restrict__ dinv,
    const float* __restrict__ bias, const float* __restrict__ W,
    unsigned short* __restrict__ Gout)
{
    int lane = threadIdx.x & 63;
    int wid  = threadIdx.x >> 6;
    float w[64];
    #pragma unroll
    for (int k = 0; k < 64; ++k) w[k] = W[k * 64 + lane];
    float bl = bias[lane];
    int n0 = (blockIdx.x * 4 + wid) * 4;
    float v0 = fmaxf(Y[(n0 + 0) * 64 + lane] + bl, 0.f);
    float v1 = fmaxf(Y[(n0 + 1) * 64 + lane] + bl, 0.f);
    float v2 = fmaxf(Y[(n0 + 2) * 64 + lane] + bl, 0.f);
    float v3 = fmaxf(Y[(n0 + 3) * 64 + lane] + bl, 0.f);
    float a0 = 0.f, a1 = 0.f, a2 = 0.f, a3 = 0.f;
    #pragma unroll
    for (int k = 0; k < 64; ++k) {
        float wk = w[k];
        a0 = fmaf(RLF(v0, k), wk, a0);
        a1 = fmaf(RLF(v1, k), wk, a1);
        a2 = fmaf(RLF(v2, k), wk, a2);
        a3 = fmaf(RLF(v3, k), wk, a3);
    }
    Gout[(n0 + 0) * 64 + lane] = bf16rtn(dinv[n0 + 0] * a0);
    Gout[(n0 + 1) * 64 + lane] = bf16rtn(dinv[n0 + 1] * a1);
    Gout[(n0 + 2) * 64 + lane] = bf16rtn(dinv[n0 + 2] * a2);
    Gout[(n0 + 3) * 64 + lane] = bf16rtn(dinv[n0 + 3] * a3);
}

// out = relu(relu(Y+b5)@fW1 + fb1) @ fW2 + fb2 — 4 nodes/wave, fW1 in VGPRs. grid NN/16.
__global__ __launch_bounds__(256, 4) void k_head(
    const float* __restrict__ Y, const float* __restrict__ b5,
    const float* __restrict__ fW1, const float* __restrict__ fb1,
    const float* __restrict__ fW2, const float* __restrict__ fb2,
    float* __restrict__ out)
{
    int lane = threadIdx.x & 63;
    int wid  = threadIdx.x >> 6;
    float w[64];
    #pragma unroll
    for (int k = 0; k < 64; ++k) w[k] = fW1[k * 64 + lane];
    float bl = b5[lane], fb1l = fb1[lane], fw2l = fW2[lane], fb2s = fb2[0];
    int n0 = (blockIdx.x * 4 + wid) * 4;
    float v0 = fmaxf(Y[(n0 + 0) * 64 + lane] + bl, 0.f);
    float v1 = fmaxf(Y[(n0 + 1) * 64 + lane] + bl, 0.f);
    float v2 = fmaxf(Y[(n0 + 2) * 64 + lane] + bl, 0.f);
    float v3 = fmaxf(Y[(n0 + 3) * 64 + lane] + bl, 0.f);
    float a0 = 0.f, a1 = 0.f, a2 = 0.f, a3 = 0.f;
    #pragma unroll
    for (int k = 0; k < 64; ++k) {
        float wk = w[k];
        a0 = fmaf(RLF(v0, k), wk, a0);
        a1 = fmaf(RLF(v1, k), wk, a1);
        a2 = fmaf(RLF(v2, k), wk, a2);
        a3 = fmaf(RLF(v3, k), wk, a3);
    }
    float t0 = fmaxf(a0 + fb1l, 0.f) * fw2l;
    float t1 = fmaxf(a1 + fb1l, 0.f) * fw2l;
    float t2 = fmaxf(a2 + fb1l, 0.f) * fw2l;
    float t3 = fmaxf(a3 + fb1l, 0.f) * fw2l;
    #pragma unroll
    for (int m = 32; m >= 1; m >>= 1) {
        t0 += __shfl_xor(t0, m, 64);
        t1 += __shfl_xor(t1, m, 64);
        t2 += __shfl_xor(t2, m, 64);
        t3 += __shfl_xor(t3, m, 64);
    }
    if (lane == 0) {
        out[n0 + 0] = t0 + fb2s;
        out[n0 + 1] = t1 + fb2s;
        out[n0 + 2] = t2 + fb2s;
        out[n0 + 3] = t3 + fb2s;
    }
}

// ---------------- Launch ----------------

extern "C" void kernel_launch(void* const* d_in, const int* in_sizes, int n_in,
                              void* d_out, int out_size, void* d_ws, size_t ws_size,
                              hipStream_t stream) {
    const float* x   = (const float*)d_in[0];
    const int*   ei  = (const int*)d_in[1];
    const float* ew  = (const float*)d_in[2];
    const float* W1  = (const float*)d_in[3];
    const float* b1  = (const float*)d_in[4];
    const float* W2  = (const float*)d_in[5];
    const float* b2  = (const float*)d_in[6];
    const float* W3  = (const float*)d_in[7];
    const float* b3  = (const float*)d_in[8];
    const float* W4  = (const float*)d_in[9];
    const float* b4  = (const float*)d_in[10];
    const float* W5  = (const float*)d_in[11];
    const float* b5  = (const float*)d_in[12];
    const float* fW1 = (const float*)d_in[13];
    const float* fb1 = (const float*)d_in[14];
    const float* fW2 = (const float*)d_in[15];
    const float* fb2 = (const float*)d_in[16];
    float* out = (float*)d_out;

    char* ws = (char*)d_ws;
    size_t o = 0;
    auto alloc = [&](size_t elems) -> void* {
        void* p = (void*)(ws + o);
        o += ((elems * 4 + 255) / 256) * 256;
        return p;
    };
    float* dinv   = (float*)alloc(NN);
    float* xd     = (float*)alloc(NN);
    int*   cnt    = (int*)alloc(NN);
    int2*  epad   = (int2*)alloc(2 * (size_t)NN * PAD);   // 38.4 MB padded rows
    float* Yb     = (float*)alloc((size_t)NN * 64);       // fp32 gather output
    unsigned* Ga16 = (unsigned*)alloc((size_t)NN * 32);   // bf16 feature rows
    unsigned* Gb16 = (unsigned*)alloc((size_t)NN * 32);

    int gE  = (EE + 255) / 256;
    int gW1 = NN / 4;                // 25000: 1 node/wave gather
    int gW4 = NN / 16;               // 6250:  4 nodes/wave

    hipMemsetAsync(cnt, 0, NN * sizeof(int), stream);
    k_cfill<<<gE, 256, 0, stream>>>(ei, ew, cnt, epad);
    k_deg<<<gW4, 256, 0, stream>>>(cnt, epad, x, dinv, xd);

    // Layer 1 (scalar gather + matvec) -> G2' bf16
    k_l1<<<gW4, 256, 0, stream>>>(xd, dinv, cnt, epad, W1, b1, W2,
                                  (unsigned short*)Ga16);
    // Layers 2..4
    k_gather<<<gW1, 256, 0, stream>>>(Ga16, dinv, cnt, epad, Yb);
    k_mv<<<gW4, 256, 0, stream>>>(Yb, dinv, b2, W3, (unsigned short*)Gb16);
    k_gather<<<gW1, 256, 0, stream>>>(Gb16, dinv, cnt, epad, Yb);
    k_mv<<<gW4, 256, 0, stream>>>(Yb, dinv, b3, W4, (unsigned short*)Ga16);
    k_gather<<<gW1, 256, 0, stream>>>(Ga16, dinv, cnt, epad, Yb);
    k_mv<<<gW4, 256, 0, stream>>>(Yb, dinv, b4, W5, (unsigned short*)Gb16);
    // Layer 5 + head
    k_gather<<<gW1, 256, 0, stream>>>(Gb16, dinv, cnt, epad, Yb);
    k_head<<<gW4, 256, 0, stream>>>(Yb, b5, fW1, fb1, fW2, fb2, out);
}

// Round 11
// 530.311 us; speedup vs baseline: 1.0754x; 1.0754x over previous
//
#include <hip/hip_runtime.h>
#include <hip/hip_bf16.h>

#define NN 100000
#define EE 1250000

#define RL(x, l) __builtin_amdgcn_readlane((x), (l))
#define RLF(x, l) __int_as_float(__builtin_amdgcn_readlane(__float_as_int(x), (l)))

__device__ __forceinline__ unsigned short bf16rtn(float x) {
    unsigned u = __float_as_uint(x);
    unsigned r = u + 0x7fffu + ((u >> 16) & 1u);
    return (unsigned short)(r >> 16);
}

// ---------------- CSR build (packed; R9-proven) ----------------
// Atomic pass: ~23 G returning atomics/s fabric ceiling (R2/R5/R9/R10), ~50us
// floor. Padded-row variant (R10) regressed: readers pay 3.8x line traffic.

__global__ __launch_bounds__(256) void k_count(const int* __restrict__ ei,
                                               int* __restrict__ cnt,
                                               int* __restrict__ slot) {
    int e = blockIdx.x * 256 + threadIdx.x;
    if (e >= EE) return;
    int d = __builtin_nontemporal_load(&ei[EE + e]);
    int s = atomicAdd(&cnt[d], 1);
    __builtin_nontemporal_store(s, &slot[e]);
}

__global__ __launch_bounds__(256) void k_bsum(const int* __restrict__ cnt, int* __restrict__ bsum) {
    __shared__ int ls[256];
    int b = blockIdx.x, tid = threadIdx.x;
    int base = b * 1024 + tid * 4;
    int s = 0;
    #pragma unroll
    for (int j = 0; j < 4; ++j) { int g = base + j; if (g < NN) s += cnt[g]; }
    ls[tid] = s; __syncthreads();
    for (int off = 128; off > 0; off >>= 1) {
        if (tid < off) ls[tid] += ls[tid + off];
        __syncthreads();
    }
    if (tid == 0) bsum[b] = ls[0];
}

// per-1024 scan; block base computed in-kernel from bsum
__global__ __launch_bounds__(256) void k_scan_out(const int* __restrict__ cnt,
                                                  const int* __restrict__ bsum,
                                                  int* __restrict__ rowptr) {
    __shared__ int ls[256];
    __shared__ int sbase;
    int b = blockIdx.x, tid = threadIdx.x;
    if (tid < 64) {
        int w0 = (tid < b) ? bsum[tid] : 0;
        int w1 = ((64 + tid) < b) ? bsum[64 + tid] : 0;
        int s = w0 + w1;
        #pragma unroll
        for (int m = 32; m >= 1; m >>= 1) s += __shfl_xor(s, m, 64);
        if (tid == 0) sbase = s;
    }
    int base = b * 1024 + tid * 4;
    int c[4]; int s = 0;
    #pragma unroll
    for (int j = 0; j < 4; ++j) {
        int g = base + j;
        c[j] = (g < NN) ? cnt[g] : 0;
        s += c[j];
    }
    ls[tid] = s; __syncthreads();
    for (int off = 1; off < 256; off <<= 1) {
        int v = (tid >= off) ? ls[tid - off] : 0;
        __syncthreads();
        ls[tid] += v;
        __syncthreads();
    }
    int excl = ls[tid] - s + sbase;
    #pragma unroll
    for (int j = 0; j < 4; ++j) {
        int g = base + j;
        if (g < NN) {
            rowptr[g + 1] = excl + c[j];
            excl += c[j];
        }
    }
    if (b == 0 && tid == 0) rowptr[0] = 0;
}

__global__ __launch_bounds__(256) void k_fill(const int* __restrict__ ei,
                                              const float* __restrict__ ew,
                                              const int* __restrict__ slot,
                                              const int* __restrict__ rowptr,
                                              int2* __restrict__ epair) {
    int e = blockIdx.x * 256 + threadIdx.x;
    if (e >= EE) return;
    int s = __builtin_nontemporal_load(&ei[e]);
    int d = __builtin_nontemporal_load(&ei[EE + e]);
    float w = __builtin_nontemporal_load(&ew[e]);
    int sl = __builtin_nontemporal_load(&slot[e]);
    int p = rowptr[d] + sl;
    epair[p] = make_int2(s, __float_as_int(w));
}

// deg[n] = 1 + sum_row ew -> dinv[n], xd[n] = dinv[n]*x[n].  4 nodes/wave.
__global__ __launch_bounds__(256) void k_deg(const int* __restrict__ rowptr,
                                             const int2* __restrict__ epair,
                                             const float* __restrict__ x,
                                             float* __restrict__ dinv,
                                             float* __restrict__ xd) {
    int lane = threadIdx.x & 63;
    int wid  = threadIdx.x >> 6;
    int l16  = lane & 15;
    int sub  = lane >> 4;
    int node = (blockIdx.x * 4 + wid) * 4 + sub;
    if (node >= NN) return;
    int beg = rowptr[node], end = rowptr[node + 1];
    float s = 0.f;
    for (int idx = beg + l16; idx < end; idx += 16)
        s += __int_as_float(epair[idx].y);
    #pragma unroll
    for (int m = 8; m >= 1; m >>= 1) s += __shfl_xor(s, m, 64);
    if (l16 == 0) {
        float di = rsqrtf(s + 1.0f);
        dinv[node] = di;
        xd[node] = di * x[node];
    }
}

// ---------------- Layers ----------------
// Identity: Agg_l[d] = dinv_d * ( G'_l[d] + sum_e w_e * G'_l[src] ), G' = dinv (.) G.
// G' stored bf16, layout [node*64 + feat] (ushort). All accumulation fp32.

// Layer 1: z scalar agg + matvec, W2 via LDS. grid NN/16.
__global__ __launch_bounds__(256) void k_l1(
    const float* __restrict__ xd, const float* __restrict__ dinv,
    const int* __restrict__ rowptr, const int2* __restrict__ ep,
    const float* __restrict__ W1, const float* __restrict__ b1,
    const float* __restrict__ W2, unsigned short* __restrict__ Gout)
{
    __shared__ float sW[4096];
    int tid = threadIdx.x;
    #pragma unroll
    for (int i = 0; i < 16; ++i) sW[tid + i * 256] = W2[tid + i * 256];
    __syncthreads();
    int lane = tid & 63, l16 = lane & 15, sub = lane >> 4;
    int g4 = blockIdx.x * 4 + (tid >> 6);
    int nodeS = g4 * 4 + sub;
    int beg = rowptr[nodeS], end = rowptr[nodeS + 1];
    float partial = 0.f;
    for (int idx = beg + l16; idx < end; idx += 16) {
        int2 p = ep[idx];
        partial = fmaf(__int_as_float(p.y), xd[p.x], partial);
    }
    #pragma unroll
    for (int m = 8; m >= 1; m >>= 1) partial += __shfl_xor(partial, m, 64);
    float z = dinv[nodeS] * (xd[nodeS] + partial);   // valid where l16==0
    float z0 = RLF(z, 0), z1 = RLF(z, 16), z2 = RLF(z, 32), z3 = RLF(z, 48);
    float w1l = W1[lane], b1l = b1[lane];
    float v0 = fmaxf(fmaf(z0, w1l, b1l), 0.f);
    float v1 = fmaxf(fmaf(z1, w1l, b1l), 0.f);
    float v2 = fmaxf(fmaf(z2, w1l, b1l), 0.f);
    float v3 = fmaxf(fmaf(z3, w1l, b1l), 0.f);
    float a0 = 0.f, a1 = 0.f, a2 = 0.f, a3 = 0.f;
    #pragma unroll
    for (int k = 0; k < 64; ++k) {
        float wk = sW[k * 64 + lane];
        a0 = fmaf(RLF(v0, k), wk, a0);
        a1 = fmaf(RLF(v1, k), wk, a1);
        a2 = fmaf(RLF(v2, k), wk, a2);
        a3 = fmaf(RLF(v3, k), wk, a3);
    }
    int n0 = g4 * 4;
    Gout[(n0 + 0) * 64 + lane] = bf16rtn(dinv[n0 + 0] * a0);
    Gout[(n0 + 1) * 64 + lane] = bf16rtn(dinv[n0 + 1] * a1);
    Gout[(n0 + 2) * 64 + lane] = bf16rtn(dinv[n0 + 2] * a2);
    Gout[(n0 + 3) * 64 + lane] = bf16rtn(dinv[n0 + 3] * a3);
}

// Gather: Y[d] = dinv_d * ( G'[d] + sum_e w_e * G'[src] ).
// One wave per node, LANE = FEATURE (ushort load: 64 lanes x 2B = one 128B row,
// one edge per load). src/weight/mask/clamp are ALL scalar-unit (ep via
// wave-uniform s_load; weight rides the fma as an SGPR operand; tail masking is
// s_cselect weight=0) -> ~3 VALU/edge vs ~9 in the half-wave scheme (R7-R10).
// 16-slot masked batch = 16 rows in flight. grid = NN/4.
__global__ __launch_bounds__(256) void k_gather(
    const unsigned short* __restrict__ Gh, const float* __restrict__ dinv,
    const int* __restrict__ rowptr, const int2* __restrict__ ep,
    float* __restrict__ Y)
{
    int tid = threadIdx.x;
    int lane = tid & 63;
    int node = __builtin_amdgcn_readfirstlane(blockIdx.x * 4 + (tid >> 6));
    int beg = __builtin_amdgcn_readfirstlane(rowptr[node]);
    int end = __builtin_amdgcn_readfirstlane(rowptr[node + 1]);
    float acc = __uint_as_float((unsigned)Gh[(size_t)node * 64 + lane] << 16);
    for (int j = beg; j < end; j += 16) {
        float h[16], nv[16];
        #pragma unroll
        for (int t = 0; t < 16; ++t) {
            int idx = j + t;                    // uniform
            bool v = idx < end;                 // uniform
            int2 p = ep[v ? idx : beg];         // s_load, scalar clamp
            nv[t] = v ? __int_as_float(p.y) : 0.f;   // s_cselect -> SGPR
            h[t] = __uint_as_float((unsigned)Gh[(size_t)p.x * 64 + lane] << 16);
        }
        #pragma unroll
        for (int t = 0; t < 16; ++t) acc = fmaf(h[t], nv[t], acc);
    }
    Y[(size_t)node * 64 + lane] = dinv[node] * acc;
}

// G' = dinv (.) ( relu(Y + bias) @ W ), bf16 out — 4 nodes/wave, W in VGPRs. grid NN/16.
__global__ __launch_bounds__(256, 4) void k_mv(
    const float* __restrict__ Y, const float* __restrict__ dinv,
    const float* __restrict__ bias, const float* __restrict__ W,
    unsigned short* __restrict__ Gout)
{
    int lane = threadIdx.x & 63;
    int wid  = threadIdx.x >> 6;
    float w[64];
    #pragma unroll
    for (int k = 0; k < 64; ++k) w[k] = W[k * 64 + lane];
    float bl = bias[lane];
    int n0 = (blockIdx.x * 4 + wid) * 4;
    float v0 = fmaxf(Y[(n0 + 0) * 64 + lane] + bl, 0.f);
    float v1 = fmaxf(Y[(n0 + 1) * 64 + lane] + bl, 0.f);
    float v2 = fmaxf(Y[(n0 + 2) * 64 + lane] + bl, 0.f);
    float v3 = fmaxf(Y[(n0 + 3) * 64 + lane] + bl, 0.f);
    float a0 = 0.f, a1 = 0.f, a2 = 0.f, a3 = 0.f;
    #pragma unroll
    for (int k = 0; k < 64; ++k) {
        float wk = w[k];
        a0 = fmaf(RLF(v0, k), wk, a0);
        a1 = fmaf(RLF(v1, k), wk, a1);
        a2 = fmaf(RLF(v2, k), wk, a2);
        a3 = fmaf(RLF(v3, k), wk, a3);
    }
    Gout[(n0 + 0) * 64 + lane] = bf16rtn(dinv[n0 + 0] * a0);
    Gout[(n0 + 1) * 64 + lane] = bf16rtn(dinv[n0 + 1] * a1);
    Gout[(n0 + 2) * 64 + lane] = bf16rtn(dinv[n0 + 2] * a2);
    Gout[(n0 + 3) * 64 + lane] = bf16rtn(dinv[n0 + 3] * a3);
}

// out = relu(relu(Y+b5)@fW1 + fb1) @ fW2 + fb2 — 4 nodes/wave, fW1 in VGPRs. grid NN/16.
__global__ __launch_bounds__(256, 4) void k_head(
    const float* __restrict__ Y, const float* __restrict__ b5,
    const float* __restrict__ fW1, const float* __restrict__ fb1,
    const float* __restrict__ fW2, const float* __restrict__ fb2,
    float* __restrict__ out)
{
    int lane = threadIdx.x & 63;
    int wid  = threadIdx.x >> 6;
    float w[64];
    #pragma unroll
    for (int k = 0; k < 64; ++k) w[k] = fW1[k * 64 + lane];
    float bl = b5[lane], fb1l = fb1[lane], fw2l = fW2[lane], fb2s = fb2[0];
    int n0 = (blockIdx.x * 4 + wid) * 4;
    float v0 = fmaxf(Y[(n0 + 0) * 64 + lane] + bl, 0.f);
    float v1 = fmaxf(Y[(n0 + 1) * 64 + lane] + bl, 0.f);
    float v2 = fmaxf(Y[(n0 + 2) * 64 + lane] + bl, 0.f);
    float v3 = fmaxf(Y[(n0 + 3) * 64 + lane] + bl, 0.f);
    float a0 = 0.f, a1 = 0.f, a2 = 0.f, a3 = 0.f;
    #pragma unroll
    for (int k = 0; k < 64; ++k) {
        float wk = w[k];
        a0 = fmaf(RLF(v0, k), wk, a0);
        a1 = fmaf(RLF(v1, k), wk, a1);
        a2 = fmaf(RLF(v2, k), wk, a2);
        a3 = fmaf(RLF(v3, k), wk, a3);
    }
    float t0 = fmaxf(a0 + fb1l, 0.f) * fw2l;
    float t1 = fmaxf(a1 + fb1l, 0.f) * fw2l;
    float t2 = fmaxf(a2 + fb1l, 0.f) * fw2l;
    float t3 = fmaxf(a3 + fb1l, 0.f) * fw2l;
    #pragma unroll
    for (int m = 32; m >= 1; m >>= 1) {
        t0 += __shfl_xor(t0, m, 64);
        t1 += __shfl_xor(t1, m, 64);
        t2 += __shfl_xor(t2, m, 64);
        t3 += __shfl_xor(t3, m, 64);
    }
    if (lane == 0) {
        out[n0 + 0] = t0 + fb2s;
        out[n0 + 1] = t1 + fb2s;
        out[n0 + 2] = t2 + fb2s;
        out[n0 + 3] = t3 + fb2s;
    }
}

// ---------------- Launch ----------------

extern "C" void kernel_launch(void* const* d_in, const int* in_sizes, int n_in,
                              void* d_out, int out_size, void* d_ws, size_t ws_size,
                              hipStream_t stream) {
    const float* x   = (const float*)d_in[0];
    const int*   ei  = (const int*)d_in[1];
    const float* ew  = (const float*)d_in[2];
    const float* W1  = (const float*)d_in[3];
    const float* b1  = (const float*)d_in[4];
    const float* W2  = (const float*)d_in[5];
    const float* b2  = (const float*)d_in[6];
    const float* W3  = (const float*)d_in[7];
    const float* b3  = (const float*)d_in[8];
    const float* W4  = (const float*)d_in[9];
    const float* b4  = (const float*)d_in[10];
    const float* W5  = (const float*)d_in[11];
    const float* b5  = (const float*)d_in[12];
    const float* fW1 = (const float*)d_in[13];
    const float* fb1 = (const float*)d_in[14];
    const float* fW2 = (const float*)d_in[15];
    const float* fb2 = (const float*)d_in[16];
    float* out = (float*)d_out;

    char* ws = (char*)d_ws;
    size_t o = 0;
    auto alloc = [&](size_t elems) -> void* {
        void* p = (void*)(ws + o);
        o += ((elems * 4 + 255) / 256) * 256;
        return p;
    };
    float* dinv   = (float*)alloc(NN);
    float* xd     = (float*)alloc(NN);
    int*   rowptr = (int*)alloc(NN + 1);
    int*   cnt    = (int*)alloc(NN);
    int*   bsum   = (int*)alloc(128);
    int2*  epair  = (int2*)alloc(2 * (size_t)EE);
    float* Yb     = (float*)alloc((size_t)NN * 64);       // fp32 gather output
    unsigned* Ga16 = (unsigned*)alloc((size_t)NN * 32);   // bf16 feature rows
    unsigned* Gb16 = (unsigned*)alloc((size_t)NN * 32);
    int*   slot   = (int*)Yb;   // aliased: slot dead (after k_fill) before Yb first written

    int gE  = (EE + 255) / 256;
    int nb  = (NN + 1023) / 1024;    // 98
    int gW1 = NN / 4;                // 25000: 1 node/wave gather
    int gW4 = NN / 16;               // 6250:  4 nodes/wave

    hipMemsetAsync(cnt, 0, NN * sizeof(int), stream);
    k_count<<<gE, 256, 0, stream>>>(ei, cnt, slot);
    k_bsum<<<nb, 256, 0, stream>>>(cnt, bsum);
    k_scan_out<<<nb, 256, 0, stream>>>(cnt, bsum, rowptr);
    k_fill<<<gE, 256, 0, stream>>>(ei, ew, slot, rowptr, epair);
    k_deg<<<gW4, 256, 0, stream>>>(rowptr, epair, x, dinv, xd);

    // Layer 1 (scalar gather + matvec) -> G2' bf16
    k_l1<<<gW4, 256, 0, stream>>>(xd, dinv, rowptr, epair, W1, b1, W2,
                                  (unsigned short*)Ga16);
    // Layers 2..4
    k_gather<<<gW1, 256, 0, stream>>>((unsigned short*)Ga16, dinv, rowptr, epair, Yb);
    k_mv<<<gW4, 256, 0, stream>>>(Yb, dinv, b2, W3, (unsigned short*)Gb16);
    k_gather<<<gW1, 256, 0, stream>>>((unsigned short*)Gb16, dinv, rowptr, epair, Yb);
    k_mv<<<gW4, 256, 0, stream>>>(Yb, dinv, b3, W4, (unsigned short*)Ga16);
    k_gather<<<gW1, 256, 0, stream>>>((unsigned short*)Ga16, dinv, rowptr, epair, Yb);
    k_mv<<<gW4, 256, 0, stream>>>(Yb, dinv, b4, W5, (unsigned short*)Gb16);
    // Layer 5 + head
    k_gather<<<gW1, 256, 0, stream>>>((unsigned short*)Gb16, dinv, rowptr, epair, Yb);
    k_head<<<gW4, 256, 0, stream>>>(Yb, b5, fW1, fb1, fW2, fb2, out);
}

// Round 12
// 504.183 us; speedup vs baseline: 1.1311x; 1.0518x over previous
//
#include <hip/hip_runtime.h>
#include <hip/hip_bf16.h>

#define NN 100000
#define EE 1250000

#define RL(x, l) __builtin_amdgcn_readlane((x), (l))
#define RLF(x, l) __int_as_float(__builtin_amdgcn_readlane(__float_as_int(x), (l)))

__device__ __forceinline__ unsigned short bf16rtn(float x) {
    unsigned u = __float_as_uint(x);
    unsigned r = u + 0x7fffu + ((u >> 16) & 1u);
    return (unsigned short)(r >> 16);
}
__device__ __forceinline__ unsigned bf16rtn2(float lo, float hi) {
    return (unsigned)bf16rtn(lo) | ((unsigned)bf16rtn(hi) << 16);
}
__device__ __forceinline__ float bflo(unsigned u) { return __uint_as_float(u << 16); }
__device__ __forceinline__ float bfhi(unsigned u) { return __uint_as_float(u & 0xffff0000u); }
__device__ __forceinline__ float bfs(unsigned short s) { return __uint_as_float((unsigned)s << 16); }

// ---------------- CSR build (packed; R9-proven) ----------------
// Atomic pass: ~23 G returning atomics/s fabric ceiling (R2/R5/R9/R10), ~50us
// floor. Padded rows (R10) and counter padding (R7) both null/regressions.

__global__ __launch_bounds__(256) void k_count(const int* __restrict__ ei,
                                               int* __restrict__ cnt,
                                               int* __restrict__ slot) {
    int e = blockIdx.x * 256 + threadIdx.x;
    if (e >= EE) return;
    int d = __builtin_nontemporal_load(&ei[EE + e]);
    int s = atomicAdd(&cnt[d], 1);
    __builtin_nontemporal_store(s, &slot[e]);
}

__global__ __launch_bounds__(256) void k_bsum(const int* __restrict__ cnt, int* __restrict__ bsum) {
    __shared__ int ls[256];
    int b = blockIdx.x, tid = threadIdx.x;
    int base = b * 1024 + tid * 4;
    int s = 0;
    #pragma unroll
    for (int j = 0; j < 4; ++j) { int g = base + j; if (g < NN) s += cnt[g]; }
    ls[tid] = s; __syncthreads();
    for (int off = 128; off > 0; off >>= 1) {
        if (tid < off) ls[tid] += ls[tid + off];
        __syncthreads();
    }
    if (tid == 0) bsum[b] = ls[0];
}

// per-1024 scan; block base computed in-kernel from bsum
__global__ __launch_bounds__(256) void k_scan_out(const int* __restrict__ cnt,
                                                  const int* __restrict__ bsum,
                                                  int* __restrict__ rowptr) {
    __shared__ int ls[256];
    __shared__ int sbase;
    int b = blockIdx.x, tid = threadIdx.x;
    if (tid < 64) {
        int w0 = (tid < b) ? bsum[tid] : 0;
        int w1 = ((64 + tid) < b) ? bsum[64 + tid] : 0;
        int s = w0 + w1;
        #pragma unroll
        for (int m = 32; m >= 1; m >>= 1) s += __shfl_xor(s, m, 64);
        if (tid == 0) sbase = s;
    }
    int base = b * 1024 + tid * 4;
    int c[4]; int s = 0;
    #pragma unroll
    for (int j = 0; j < 4; ++j) {
        int g = base + j;
        c[j] = (g < NN) ? cnt[g] : 0;
        s += c[j];
    }
    ls[tid] = s; __syncthreads();
    for (int off = 1; off < 256; off <<= 1) {
        int v = (tid >= off) ? ls[tid - off] : 0;
        __syncthreads();
        ls[tid] += v;
        __syncthreads();
    }
    int excl = ls[tid] - s + sbase;
    #pragma unroll
    for (int j = 0; j < 4; ++j) {
        int g = base + j;
        if (g < NN) {
            rowptr[g + 1] = excl + c[j];
            excl += c[j];
        }
    }
    if (b == 0 && tid == 0) rowptr[0] = 0;
}

__global__ __launch_bounds__(256) void k_fill(const int* __restrict__ ei,
                                              const float* __restrict__ ew,
                                              const int* __restrict__ slot,
                                              const int* __restrict__ rowptr,
                                              int2* __restrict__ epair) {
    int e = blockIdx.x * 256 + threadIdx.x;
    if (e >= EE) return;
    int s = __builtin_nontemporal_load(&ei[e]);
    int d = __builtin_nontemporal_load(&ei[EE + e]);
    float w = __builtin_nontemporal_load(&ew[e]);
    int sl = __builtin_nontemporal_load(&slot[e]);
    int p = rowptr[d] + sl;
    epair[p] = make_int2(s, __float_as_int(w));
}

// deg[n] = 1 + sum_row ew -> dinv[n], xd[n] = dinv[n]*x[n].  4 nodes/wave.
__global__ __launch_bounds__(256) void k_deg(const int* __restrict__ rowptr,
                                             const int2* __restrict__ epair,
                                             const float* __restrict__ x,
                                             float* __restrict__ dinv,
                                             float* __restrict__ xd) {
    int lane = threadIdx.x & 63;
    int wid  = threadIdx.x >> 6;
    int l16  = lane & 15;
    int sub  = lane >> 4;
    int node = (blockIdx.x * 4 + wid) * 4 + sub;
    if (node >= NN) return;
    int beg = rowptr[node], end = rowptr[node + 1];
    float s = 0.f;
    for (int idx = beg + l16; idx < end; idx += 16)
        s += __int_as_float(epair[idx].y);
    #pragma unroll
    for (int m = 8; m >= 1; m >>= 1) s += __shfl_xor(s, m, 64);
    if (l16 == 0) {
        float di = rsqrtf(s + 1.0f);
        dinv[node] = di;
        xd[node] = di * x[node];
    }
}

// ---------------- Layers ----------------
// Identity: Agg_l[d] = dinv_d * ( G'_l[d] + sum_e w_e * G'_l[src] ), G' = dinv (.) G.
// G' AND Y stored bf16 (rows = 32 uints = 128 B). All accumulation fp32.

// Layer 1: z scalar agg + matvec, W2 via LDS. grid NN/16.
__global__ __launch_bounds__(256) void k_l1(
    const float* __restrict__ xd, const float* __restrict__ dinv,
    const int* __restrict__ rowptr, const int2* __restrict__ ep,
    const float* __restrict__ W1, const float* __restrict__ b1,
    const float* __restrict__ W2, unsigned short* __restrict__ Gout)
{
    __shared__ float sW[4096];
    int tid = threadIdx.x;
    #pragma unroll
    for (int i = 0; i < 16; ++i) sW[tid + i * 256] = W2[tid + i * 256];
    __syncthreads();
    int lane = tid & 63, l16 = lane & 15, sub = lane >> 4;
    int g4 = blockIdx.x * 4 + (tid >> 6);
    int nodeS = g4 * 4 + sub;
    int beg = rowptr[nodeS], end = rowptr[nodeS + 1];
    float partial = 0.f;
    for (int idx = beg + l16; idx < end; idx += 16) {
        int2 p = ep[idx];
        partial = fmaf(__int_as_float(p.y), xd[p.x], partial);
    }
    #pragma unroll
    for (int m = 8; m >= 1; m >>= 1) partial += __shfl_xor(partial, m, 64);
    float z = dinv[nodeS] * (xd[nodeS] + partial);   // valid where l16==0
    float z0 = RLF(z, 0), z1 = RLF(z, 16), z2 = RLF(z, 32), z3 = RLF(z, 48);
    float w1l = W1[lane], b1l = b1[lane];
    float v0 = fmaxf(fmaf(z0, w1l, b1l), 0.f);
    float v1 = fmaxf(fmaf(z1, w1l, b1l), 0.f);
    float v2 = fmaxf(fmaf(z2, w1l, b1l), 0.f);
    float v3 = fmaxf(fmaf(z3, w1l, b1l), 0.f);
    float a0 = 0.f, a1 = 0.f, a2 = 0.f, a3 = 0.f;
    #pragma unroll
    for (int k = 0; k < 64; ++k) {
        float wk = sW[k * 64 + lane];
        a0 = fmaf(RLF(v0, k), wk, a0);
        a1 = fmaf(RLF(v1, k), wk, a1);
        a2 = fmaf(RLF(v2, k), wk, a2);
        a3 = fmaf(RLF(v3, k), wk, a3);
    }
    int n0 = g4 * 4;
    Gout[(n0 + 0) * 64 + lane] = bf16rtn(dinv[n0 + 0] * a0);
    Gout[(n0 + 1) * 64 + lane] = bf16rtn(dinv[n0 + 1] * a1);
    Gout[(n0 + 2) * 64 + lane] = bf16rtn(dinv[n0 + 2] * a2);
    Gout[(n0 + 3) * 64 + lane] = bf16rtn(dinv[n0 + 3] * a3);
}

// Gather over bf16 rows (R7-proven half-wave shape — best of 4 measured
// structures): one wave per node; 16-edge batches = 8 row-loads in flight,
// 2 edges per dword load (wave halves); ep indices wave-uniform -> s_load;
// masked tail clamps to ep[j]. Y output bf16 (packed uint per column pair).
// grid = NN/4.
__global__ __launch_bounds__(256) void k_gather(
    const unsigned* __restrict__ G16, const float* __restrict__ dinv,
    const int* __restrict__ rowptr, const int2* __restrict__ ep,
    unsigned* __restrict__ Yh)
{
    int tid = threadIdx.x;
    int lane = tid & 63;
    int lc = lane & 31;
    int half = lane >> 5;
    int node = blockIdx.x * 4 + (tid >> 6);
    int beg = __builtin_amdgcn_readfirstlane(rowptr[node]);
    int end = __builtin_amdgcn_readfirstlane(rowptr[node + 1]);
    float ax = 0.f, ay = 0.f;
    if (half == 0) {
        unsigned u = G16[node * 32 + lc];
        ax = bflo(u); ay = bfhi(u);
    }
    int j = beg;
    for (; j + 16 <= end; j += 16) {          // full batch: 16 edges, 8 loads
        unsigned u[8]; float nv[8];
        #pragma unroll
        for (int t = 0; t < 8; ++t) {
            int2 pa = ep[j + t];              // uniform -> s_load
            int2 pb = ep[j + 8 + t];          // uniform -> s_load
            int src = half ? pb.x : pa.x;
            nv[t] = __int_as_float(half ? pb.y : pa.y);
            u[t] = G16[src * 32 + lc];
        }
        #pragma unroll
        for (int t = 0; t < 8; ++t) {
            ax = fmaf(bflo(u[t]), nv[t], ax);
            ay = fmaf(bfhi(u[t]), nv[t], ay);
        }
    }
    if (j < end) {                            // masked batch (tail 1..15)
        unsigned u[8]; float nv[8];
        #pragma unroll
        for (int t = 0; t < 8; ++t) {
            int ia = j + t, ib = j + 8 + t;   // uniform
            int2 pa = ep[ia < end ? ia : j];
            int2 pb = ep[ib < end ? ib : j];
            int src = half ? pb.x : pa.x;
            float w = __int_as_float(half ? pb.y : pa.y);
            bool v = half ? (ib < end) : (ia < end);
            nv[t] = v ? w : 0.f;
            u[t] = G16[src * 32 + lc];
        }
        #pragma unroll
        for (int t = 0; t < 8; ++t) {
            ax = fmaf(bflo(u[t]), nv[t], ax);
            ay = fmaf(bfhi(u[t]), nv[t], ay);
        }
    }
    ax += __shfl_xor(ax, 32, 64);
    ay += __shfl_xor(ay, 32, 64);
    if (half == 0) {
        float din = dinv[node];
        Yh[node * 32 + lc] = bf16rtn2(din * ax, din * ay);
    }
}

// G' = dinv (.) ( relu(Y + bias) @ W ), bf16 in/out — 4 nodes/wave, W in VGPRs. grid NN/16.
__global__ __launch_bounds__(256, 4) void k_mv(
    const unsigned short* __restrict__ Yh, const float* __restrict__ dinv,
    const float* __restrict__ bias, const float* __restrict__ W,
    unsigned short* __restrict__ Gout)
{
    int lane = threadIdx.x & 63;
    int wid  = threadIdx.x >> 6;
    float w[64];
    #pragma unroll
    for (int k = 0; k < 64; ++k) w[k] = W[k * 64 + lane];
    float bl = bias[lane];
    int n0 = (blockIdx.x * 4 + wid) * 4;
    float v0 = fmaxf(bfs(Yh[(n0 + 0) * 64 + lane]) + bl, 0.f);
    float v1 = fmaxf(bfs(Yh[(n0 + 1) * 64 + lane]) + bl, 0.f);
    float v2 = fmaxf(bfs(Yh[(n0 + 2) * 64 + lane]) + bl, 0.f);
    float v3 = fmaxf(bfs(Yh[(n0 + 3) * 64 + lane]) + bl, 0.f);
    float a0 = 0.f, a1 = 0.f, a2 = 0.f, a3 = 0.f;
    #pragma unroll
    for (int k = 0; k < 64; ++k) {
        float wk = w[k];
        a0 = fmaf(RLF(v0, k), wk, a0);
        a1 = fmaf(RLF(v1, k), wk, a1);
        a2 = fmaf(RLF(v2, k), wk, a2);
        a3 = fmaf(RLF(v3, k), wk, a3);
    }
    Gout[(n0 + 0) * 64 + lane] = bf16rtn(dinv[n0 + 0] * a0);
    Gout[(n0 + 1) * 64 + lane] = bf16rtn(dinv[n0 + 1] * a1);
    Gout[(n0 + 2) * 64 + lane] = bf16rtn(dinv[n0 + 2] * a2);
    Gout[(n0 + 3) * 64 + lane] = bf16rtn(dinv[n0 + 3] * a3);
}

// out = relu(relu(Y+b5)@fW1 + fb1) @ fW2 + fb2 — 4 nodes/wave, fW1 in VGPRs. grid NN/16.
__global__ __launch_bounds__(256, 4) void k_head(
    const unsigned short* __restrict__ Yh, const float* __restrict__ b5,
    const float* __restrict__ fW1, const float* __restrict__ fb1,
    const float* __restrict__ fW2, const float* __restrict__ fb2,
    float* __restrict__ out)
{
    int lane = threadIdx.x & 63;
    int wid  = threadIdx.x >> 6;
    float w[64];
    #pragma unroll
    for (int k = 0; k < 64; ++k) w[k] = fW1[k * 64 + lane];
    float bl = b5[lane], fb1l = fb1[lane], fw2l = fW2[lane], fb2s = fb2[0];
    int n0 = (blockIdx.x * 4 + wid) * 4;
    float v0 = fmaxf(bfs(Yh[(n0 + 0) * 64 + lane]) + bl, 0.f);
    float v1 = fmaxf(bfs(Yh[(n0 + 1) * 64 + lane]) + bl, 0.f);
    float v2 = fmaxf(bfs(Yh[(n0 + 2) * 64 + lane]) + bl, 0.f);
    float v3 = fmaxf(bfs(Yh[(n0 + 3) * 64 + lane]) + bl, 0.f);
    float a0 = 0.f, a1 = 0.f, a2 = 0.f, a3 = 0.f;
    #pragma unroll
    for (int k = 0; k < 64; ++k) {
        float wk = w[k];
        a0 = fmaf(RLF(v0, k), wk, a0);
        a1 = fmaf(RLF(v1, k), wk, a1);
        a2 = fmaf(RLF(v2, k), wk, a2);
        a3 = fmaf(RLF(v3, k), wk, a3);
    }
    float t0 = fmaxf(a0 + fb1l, 0.f) * fw2l;
    float t1 = fmaxf(a1 + fb1l, 0.f) * fw2l;
    float t2 = fmaxf(a2 + fb1l, 0.f) * fw2l;
    float t3 = fmaxf(a3 + fb1l, 0.f) * fw2l;
    #pragma unroll
    for (int m = 32; m >= 1; m >>= 1) {
        t0 += __shfl_xor(t0, m, 64);
        t1 += __shfl_xor(t1, m, 64);
        t2 += __shfl_xor(t2, m, 64);
        t3 += __shfl_xor(t3, m, 64);
    }
    if (lane == 0) {
        out[n0 + 0] = t0 + fb2s;
        out[n0 + 1] = t1 + fb2s;
        out[n0 + 2] = t2 + fb2s;
        out[n0 + 3] = t3 + fb2s;
    }
}

// ---------------- Launch ----------------

extern "C" void kernel_launch(void* const* d_in, const int* in_sizes, int n_in,
                              void* d_out, int out_size, void* d_ws, size_t ws_size,
                              hipStream_t stream) {
    const float* x   = (const float*)d_in[0];
    const int*   ei  = (const int*)d_in[1];
    const float* ew  = (const float*)d_in[2];
    const float* W1  = (const float*)d_in[3];
    const float* b1  = (const float*)d_in[4];
    const float* W2  = (const float*)d_in[5];
    const float* b2  = (const float*)d_in[6];
    const float* W3  = (const float*)d_in[7];
    const float* b3  = (const float*)d_in[8];
    const float* W4  = (const float*)d_in[9];
    const float* b4  = (const float*)d_in[10];
    const float* W5  = (const float*)d_in[11];
    const float* b5  = (const float*)d_in[12];
    const float* fW1 = (const float*)d_in[13];
    const float* fb1 = (const float*)d_in[14];
    const float* fW2 = (const float*)d_in[15];
    const float* fb2 = (const float*)d_in[16];
    float* out = (float*)d_out;

    char* ws = (char*)d_ws;
    size_t o = 0;
    auto alloc = [&](size_t elems) -> void* {
        void* p = (void*)(ws + o);
        o += ((elems * 4 + 255) / 256) * 256;
        return p;
    };
    float* dinv   = (float*)alloc(NN);
    float* xd     = (float*)alloc(NN);
    int*   rowptr = (int*)alloc(NN + 1);
    int*   cnt    = (int*)alloc(NN);
    int*   bsum   = (int*)alloc(128);
    int2*  epair  = (int2*)alloc(2 * (size_t)EE);
    unsigned* Yh   = (unsigned*)alloc((size_t)NN * 32);   // bf16 gather output
    unsigned* Ga16 = (unsigned*)alloc((size_t)NN * 32);   // bf16 feature rows
    unsigned* Gb16 = (unsigned*)alloc((size_t)NN * 32);
    int*   slot   = (int*)alloc(EE);   // dedicated (Yh too small to alias)

    int gE  = (EE + 255) / 256;
    int nb  = (NN + 1023) / 1024;    // 98
    int gW1 = NN / 4;                // 25000: 1 node/wave gather
    int gW4 = NN / 16;               // 6250:  4 nodes/wave

    hipMemsetAsync(cnt, 0, NN * sizeof(int), stream);
    k_count<<<gE, 256, 0, stream>>>(ei, cnt, slot);
    k_bsum<<<nb, 256, 0, stream>>>(cnt, bsum);
    k_scan_out<<<nb, 256, 0, stream>>>(cnt, bsum, rowptr);
    k_fill<<<gE, 256, 0, stream>>>(ei, ew, slot, rowptr, epair);
    k_deg<<<gW4, 256, 0, stream>>>(rowptr, epair, x, dinv, xd);

    // Layer 1 (scalar gather + matvec) -> G2' bf16
    k_l1<<<gW4, 256, 0, stream>>>(xd, dinv, rowptr, epair, W1, b1, W2,
                                  (unsigned short*)Ga16);
    // Layers 2..4
    k_gather<<<gW1, 256, 0, stream>>>(Ga16, dinv, rowptr, epair, Yh);
    k_mv<<<gW4, 256, 0, stream>>>((unsigned short*)Yh, dinv, b2, W3, (unsigned short*)Gb16);
    k_gather<<<gW1, 256, 0, stream>>>(Gb16, dinv, rowptr, epair, Yh);
    k_mv<<<gW4, 256, 0, stream>>>((unsigned short*)Yh, dinv, b3, W4, (unsigned short*)Ga16);
    k_gather<<<gW1, 256, 0, stream>>>(Ga16, dinv, rowptr, epair, Yh);
    k_mv<<<gW4, 256, 0, stream>>>((unsigned short*)Yh, dinv, b4, W5, (unsigned short*)Gb16);
    // Layer 5 + head
    k_gather<<<gW1, 256, 0, stream>>>(Gb16, dinv, rowptr, epair, Yh);
    k_head<<<gW4, 256, 0, stream>>>((unsigned short*)Yh, b5, fW1, fb1, fW2, fb2, out);
}